// Round 4
// baseline (3073.790 us; speedup 1.0000x reference)
//
#include <hip/hip_runtime.h>

// 2-layer LSTM encoder, fused single kernel, v4.
// Same schedule as v3 (one barrier/step, gate-gather via intra-wave shuffles,
// layer pipeline: iter n = layer1 step n + layer2 step n-1, both reading
// h1(n-1)), with the Round-3 bottleneck fixed:
//   * Weights live in NAMED float4 registers (wh0..wh15, wx) — v3's float
//     arrays were demoted to scratch (VGPR_Count=80 < 90+ live floats) and
//     re-loaded 84 dwords/lane/iteration. Named float4 SSA values cannot be
//     demoted, and __launch_bounds__(512,2) truthfully allows 256 VGPR/wave.
//   * x[b,t,:] staged through a 2-chunk LDS ring: wave 0 does one coalesced
//     global load + ds_write per 64 steps; per step all l1 lanes do one
//     broadcast ds_read_b128. No per-step global load on the critical path.
//   * exp2f-based activations (log2e folded into per-lane constants):
//     one v_exp_f32 + one v_rcp_f32 per activation.
// Layout: 64 blocks (one per batch element), 512 threads = 8 waves:
//   waves 0..3: layer-1, 16 units/wave, lane = 16*type + unit. 68 FMAs/lane.
//   waves 4..7: layer-2, 8 units/wave, lane = 16*type + 2*unit + half.
//               48 FMAs/lane, lane-pair combined via shfl_xor(.,1).

#define BATCH 64
#define T 4096
#define IN_DIM 4
#define H1 64
#define H2 32
#define NTHREADS 512
#define L2E 1.442695040888963f

__device__ __forceinline__ float fast_rcp(float v) { return __builtin_amdgcn_rcpf(v); }

__global__ __launch_bounds__(NTHREADS, 2)
void lstm2_fused_v4(const float* __restrict__ x,
                    const float* __restrict__ W_ih1, const float* __restrict__ W_hh1,
                    const float* __restrict__ b_ih1, const float* __restrict__ b_hh1,
                    const float* __restrict__ W_ih2, const float* __restrict__ W_hh2,
                    const float* __restrict__ b_ih2, const float* __restrict__ b_hh2,
                    float* __restrict__ out)
{
    const int b    = blockIdx.x;
    const int tid  = threadIdx.x;
    const int wave = tid >> 6;
    const int lane = tid & 63;
    const bool is_l1 = (wave < 4);
    const int type = lane >> 4;        // 0=i 1=f 2=g 3=o
    const int base = lane & 15;        // type-0 lane of my unit
    const int half = lane & 1;         // layer-2 dot-product half

    __shared__ __align__(16) float h1buf[2][H1];
    __shared__ __align__(16) float h2buf[2][H2];
    __shared__ __align__(16) float xbuf[2][64][IN_DIM];  // 2-chunk x ring

    if (tid < 2 * H1)                    ((float*)h1buf)[tid] = 0.0f;
    else if (tid < 2 * H1 + 2 * H2)      ((float*)h2buf)[tid - 2 * H1] = 0.0f;

    // act = sc_out * rcp(1 + exp2(sc_in2*acc)) + sc_off
    // type!=2: sigmoid;  type==2: tanh(x) = 2/(1+exp(-2x)) - 1
    const float sc_in2 = (type == 2) ? -2.0f * L2E : -L2E;
    const float sc_out = (type == 2) ?  2.0f :  1.0f;
    const float sc_off = (type == 2) ? -1.0f :  0.0f;

    // ---- weights in NAMED registers ----
    float4 wh0, wh1, wh2, wh3, wh4, wh5, wh6, wh7;
    float4 wh8, wh9, wh10, wh11, wh12, wh13, wh14, wh15;
    float4 wx = make_float4(0.f, 0.f, 0.f, 0.f);
    float bias;
    int   j;
    float c = 0.0f;

    if (is_l1) {
        j = 16 * wave + base;
        const int g = type * H1 + j;
        const float4* wr = (const float4*)(W_hh1 + (size_t)g * H1);
        wh0  = wr[0];  wh1  = wr[1];  wh2  = wr[2];  wh3  = wr[3];
        wh4  = wr[4];  wh5  = wr[5];  wh6  = wr[6];  wh7  = wr[7];
        wh8  = wr[8];  wh9  = wr[9];  wh10 = wr[10]; wh11 = wr[11];
        wh12 = wr[12]; wh13 = wr[13]; wh14 = wr[14]; wh15 = wr[15];
        wx = *(const float4*)(W_ih1 + (size_t)g * IN_DIM);
        bias = b_ih1[g] + b_hh1[g];
    } else {
        j = 8 * (wave - 4) + (base >> 1);
        const int g = type * H2 + j;
        const float4* wi = (const float4*)(W_ih2 + (size_t)g * H1) + (half << 3);
        wh0 = wi[0]; wh1 = wi[1]; wh2 = wi[2]; wh3 = wi[3];
        wh4 = wi[4]; wh5 = wi[5]; wh6 = wi[6]; wh7 = wi[7];
        const float4* wp = (const float4*)(W_hh2 + (size_t)g * H2) + (half << 2);
        wh8 = wp[0]; wh9 = wp[1]; wh10 = wp[2]; wh11 = wp[3];
        wh12 = wh13 = wh14 = wh15 = make_float4(0.f, 0.f, 0.f, 0.f);
        bias = half ? 0.0f : (b_ih2[g] + b_hh2[g]);   // only half 0 carries bias
    }

    const float4* xptr = (const float4*)(x + (size_t)b * T * IN_DIM);
    float4 xg = make_float4(0.f, 0.f, 0.f, 0.f);
    if (wave == 0) {
        float4 x0 = xptr[lane];                       // chunk 0
        *(float4*)&xbuf[0][lane][0] = x0;
        xg = xptr[64 + lane];                         // chunk 1 in flight
    }
    float* outb = out + (size_t)b * T * H2;

    __syncthreads();

#define FMA4(W, HH) do { a0 = fmaf((HH).x, (W).x, a0); a1 = fmaf((HH).y, (W).y, a1); \
                         a2 = fmaf((HH).z, (W).z, a2); a3 = fmaf((HH).w, (W).w, a3); } while (0)

    for (int n = 0; n <= T; ++n) {
        if (is_l1) {
            if (n < T) {
                const int s = n & 63, cch = n >> 6;
                if (s == 0 && wave == 0) {
                    // publish chunk cch+1; start load of chunk cch+2
                    *(float4*)&xbuf[(cch + 1) & 1][lane][0] = xg;
                    const int nb = (cch + 2) << 6;
                    if (nb < T) xg = xptr[nb + lane];
                }
                float a0 = bias, a1 = 0.f, a2 = 0.f, a3 = 0.f;
                const float4* hv = (const float4*)h1buf[(n + 1) & 1];   // h1(n-1)
                float4 hh;
                hh = hv[0];  FMA4(wh0,  hh);
                hh = hv[1];  FMA4(wh1,  hh);
                hh = hv[2];  FMA4(wh2,  hh);
                hh = hv[3];  FMA4(wh3,  hh);
                hh = hv[4];  FMA4(wh4,  hh);
                hh = hv[5];  FMA4(wh5,  hh);
                hh = hv[6];  FMA4(wh6,  hh);
                hh = hv[7];  FMA4(wh7,  hh);
                hh = hv[8];  FMA4(wh8,  hh);
                hh = hv[9];  FMA4(wh9,  hh);
                hh = hv[10]; FMA4(wh10, hh);
                hh = hv[11]; FMA4(wh11, hh);
                hh = hv[12]; FMA4(wh12, hh);
                hh = hv[13]; FMA4(wh13, hh);
                hh = hv[14]; FMA4(wh14, hh);
                hh = hv[15]; FMA4(wh15, hh);
                float4 xt = *(const float4*)&xbuf[cch & 1][s][0];       // broadcast
                FMA4(wx, xt);
                float acc = (a0 + a1) + (a2 + a3);
                float act = fmaf(sc_out, fast_rcp(1.0f + exp2f(sc_in2 * acc)), sc_off);
                float gi = __shfl(act, base,      64);
                float gf = __shfl(act, base + 16, 64);
                float gg = __shfl(act, base + 32, 64);
                float go = __shfl(act, base + 48, 64);
                c = fmaf(gf, c, gi * gg);
                float th = 1.0f - 2.0f * fast_rcp(exp2f(2.0f * L2E * c) + 1.0f);
                float h = go * th;
                if (lane < 16) h1buf[n & 1][j] = h;
            }
        } else {
            if (n >= 1) {
                float a0 = bias, a1 = 0.f, a2 = 0.f, a3 = 0.f;
                const float4* hv = (const float4*)h1buf[(n + 1) & 1] + (half << 3); // h1(n-1)
                float4 hh;
                hh = hv[0]; FMA4(wh0, hh);
                hh = hv[1]; FMA4(wh1, hh);
                hh = hv[2]; FMA4(wh2, hh);
                hh = hv[3]; FMA4(wh3, hh);
                hh = hv[4]; FMA4(wh4, hh);
                hh = hv[5]; FMA4(wh5, hh);
                hh = hv[6]; FMA4(wh6, hh);
                hh = hv[7]; FMA4(wh7, hh);
                const float4* h2v = (const float4*)h2buf[n & 1] + (half << 2);      // h2(n-2)
                hh = h2v[0]; FMA4(wh8,  hh);
                hh = h2v[1]; FMA4(wh9,  hh);
                hh = h2v[2]; FMA4(wh10, hh);
                hh = h2v[3]; FMA4(wh11, hh);
                float part = (a0 + a1) + (a2 + a3);
                float acc = part + __shfl_xor(part, 1, 64);   // combine lane pair
                float act = fmaf(sc_out, fast_rcp(1.0f + exp2f(sc_in2 * acc)), sc_off);
                float gi = __shfl(act, base,      64);
                float gf = __shfl(act, base + 16, 64);
                float gg = __shfl(act, base + 32, 64);
                float go = __shfl(act, base + 48, 64);
                c = fmaf(gf, c, gi * gg);
                float th = 1.0f - 2.0f * fast_rcp(exp2f(2.0f * L2E * c) + 1.0f);
                float h = go * th;
                if ((lane & 49) == 0) {            // type==0 && half==0
                    h2buf[(n + 1) & 1][j] = h;
                    outb[(size_t)(n - 1) * H2 + j] = h;
                }
            }
        }
        __syncthreads();
    }
#undef FMA4
}

extern "C" void kernel_launch(void* const* d_in, const int* in_sizes, int n_in,
                              void* d_out, int out_size, void* d_ws, size_t ws_size,
                              hipStream_t stream) {
    const float* x     = (const float*)d_in[0];
    const float* W_ih1 = (const float*)d_in[1];
    const float* W_hh1 = (const float*)d_in[2];
    const float* b_ih1 = (const float*)d_in[3];
    const float* b_hh1 = (const float*)d_in[4];
    const float* W_ih2 = (const float*)d_in[5];
    const float* W_hh2 = (const float*)d_in[6];
    const float* b_ih2 = (const float*)d_in[7];
    const float* b_hh2 = (const float*)d_in[8];
    float* out = (float*)d_out;

    lstm2_fused_v4<<<dim3(BATCH), dim3(NTHREADS), 0, stream>>>(
        x, W_ih1, W_hh1, b_ih1, b_hh1, W_ih2, W_hh2, b_ih2, b_hh2, out);
}

// Round 5
// 2501.752 us; speedup vs baseline: 1.2287x; 1.2287x over previous
//
#include <hip/hip_runtime.h>

// 2-layer LSTM encoder, fused single kernel, v5 = v4 + amdgpu_waves_per_eu(2,2).
//
// ROUND-4 FINDING: with only a *minimum* waves/EU declared, the AMDGPU
// allocator targeted max occupancy (8 waves/EU -> 64-VGPR budget) and
// reloaded all 68 per-lane weight floats from memory EVERY timestep
// (VGPR_Count=64; v3 same disease at 80). We run exactly 1 block/CU
// (64 blocks, 256 CUs) = 2 waves/EU, so that occupancy is worthless.
// amdgpu_waves_per_eu(2,2) sets max=2 -> 256-VGPR budget, no incentive to
// shrink -> weights stay register-resident across the whole T-loop.
//
// Schedule (unchanged from v4):
//   64 blocks (one per batch element), 512 threads = 8 waves.
//   waves 0..3: layer-1, 16 units/wave, lane = 16*type + unit. 68 FMAs/lane.
//   waves 4..7: layer-2, 8 units/wave, lane = 16*type + 2*unit + half.
//               48 FMAs/lane, lane-pair combined via shfl_xor(.,1).
//   Iteration n = layer-1 step n + layer-2 step n-1; both read h1(n-1);
//   ONE __syncthreads per step; gates gathered via intra-wave shuffles;
//   c,h updated redundantly in-register. x staged via 2-chunk LDS ring.

#define BATCH 64
#define T 4096
#define IN_DIM 4
#define H1 64
#define H2 32
#define NTHREADS 512
#define L2E 1.442695040888963f

__device__ __forceinline__ float fast_rcp(float v) { return __builtin_amdgcn_rcpf(v); }

__global__ __launch_bounds__(NTHREADS)
__attribute__((amdgpu_waves_per_eu(2, 2)))
void lstm2_fused_v5(const float* __restrict__ x,
                    const float* __restrict__ W_ih1, const float* __restrict__ W_hh1,
                    const float* __restrict__ b_ih1, const float* __restrict__ b_hh1,
                    const float* __restrict__ W_ih2, const float* __restrict__ W_hh2,
                    const float* __restrict__ b_ih2, const float* __restrict__ b_hh2,
                    float* __restrict__ out)
{
    const int b    = blockIdx.x;
    const int tid  = threadIdx.x;
    const int wave = tid >> 6;
    const int lane = tid & 63;
    const bool is_l1 = (wave < 4);
    const int type = lane >> 4;        // 0=i 1=f 2=g 3=o
    const int base = lane & 15;        // type-0 lane of my unit
    const int half = lane & 1;         // layer-2 dot-product half

    __shared__ __align__(16) float h1buf[2][H1];
    __shared__ __align__(16) float h2buf[2][H2];
    __shared__ __align__(16) float xbuf[2][64][IN_DIM];  // 2-chunk x ring

    if (tid < 2 * H1)                    ((float*)h1buf)[tid] = 0.0f;
    else if (tid < 2 * H1 + 2 * H2)      ((float*)h2buf)[tid - 2 * H1] = 0.0f;

    // act = sc_out * rcp(1 + exp2(sc_in2*acc)) + sc_off
    // type!=2: sigmoid;  type==2: tanh(x) = 2/(1+exp(-2x)) - 1
    const float sc_in2 = (type == 2) ? -2.0f * L2E : -L2E;
    const float sc_out = (type == 2) ?  2.0f :  1.0f;
    const float sc_off = (type == 2) ? -1.0f :  0.0f;

    // ---- weights in registers (budget 256 VGPR/wave via waves_per_eu(2,2)) ----
    float4 wh0, wh1, wh2, wh3, wh4, wh5, wh6, wh7;
    float4 wh8, wh9, wh10, wh11, wh12, wh13, wh14, wh15;
    float4 wx = make_float4(0.f, 0.f, 0.f, 0.f);
    float bias;
    int   j;
    float c = 0.0f;

    if (is_l1) {
        j = 16 * wave + base;
        const int g = type * H1 + j;
        const float4* wr = (const float4*)(W_hh1 + (size_t)g * H1);
        wh0  = wr[0];  wh1  = wr[1];  wh2  = wr[2];  wh3  = wr[3];
        wh4  = wr[4];  wh5  = wr[5];  wh6  = wr[6];  wh7  = wr[7];
        wh8  = wr[8];  wh9  = wr[9];  wh10 = wr[10]; wh11 = wr[11];
        wh12 = wr[12]; wh13 = wr[13]; wh14 = wr[14]; wh15 = wr[15];
        wx = *(const float4*)(W_ih1 + (size_t)g * IN_DIM);
        bias = b_ih1[g] + b_hh1[g];
    } else {
        j = 8 * (wave - 4) + (base >> 1);
        const int g = type * H2 + j;
        const float4* wi = (const float4*)(W_ih2 + (size_t)g * H1) + (half << 3);
        wh0 = wi[0]; wh1 = wi[1]; wh2 = wi[2]; wh3 = wi[3];
        wh4 = wi[4]; wh5 = wi[5]; wh6 = wi[6]; wh7 = wi[7];
        const float4* wp = (const float4*)(W_hh2 + (size_t)g * H2) + (half << 2);
        wh8 = wp[0]; wh9 = wp[1]; wh10 = wp[2]; wh11 = wp[3];
        wh12 = wh13 = wh14 = wh15 = make_float4(0.f, 0.f, 0.f, 0.f);
        bias = half ? 0.0f : (b_ih2[g] + b_hh2[g]);   // only half 0 carries bias
    }

    const float4* xptr = (const float4*)(x + (size_t)b * T * IN_DIM);
    float4 xg = make_float4(0.f, 0.f, 0.f, 0.f);
    if (wave == 0) {
        float4 x0 = xptr[lane];                       // chunk 0
        *(float4*)&xbuf[0][lane][0] = x0;
        xg = xptr[64 + lane];                         // chunk 1 in flight
    }
    float* outb = out + (size_t)b * T * H2;

    __syncthreads();

#define FMA4(W, HH) do { a0 = fmaf((HH).x, (W).x, a0); a1 = fmaf((HH).y, (W).y, a1); \
                         a2 = fmaf((HH).z, (W).z, a2); a3 = fmaf((HH).w, (W).w, a3); } while (0)

    for (int n = 0; n <= T; ++n) {
        if (is_l1) {
            if (n < T) {
                const int s = n & 63, cch = n >> 6;
                if (s == 0 && wave == 0) {
                    // publish chunk cch+1 into the idle ring slot; prefetch cch+2
                    *(float4*)&xbuf[(cch + 1) & 1][lane][0] = xg;
                    const int nb = (cch + 2) << 6;
                    if (nb < T) xg = xptr[nb + lane];
                }
                float a0 = bias, a1 = 0.f, a2 = 0.f, a3 = 0.f;
                const float4* hv = (const float4*)h1buf[(n + 1) & 1];   // h1(n-1)
                float4 hh;
                hh = hv[0];  FMA4(wh0,  hh);
                hh = hv[1];  FMA4(wh1,  hh);
                hh = hv[2];  FMA4(wh2,  hh);
                hh = hv[3];  FMA4(wh3,  hh);
                hh = hv[4];  FMA4(wh4,  hh);
                hh = hv[5];  FMA4(wh5,  hh);
                hh = hv[6];  FMA4(wh6,  hh);
                hh = hv[7];  FMA4(wh7,  hh);
                hh = hv[8];  FMA4(wh8,  hh);
                hh = hv[9];  FMA4(wh9,  hh);
                hh = hv[10]; FMA4(wh10, hh);
                hh = hv[11]; FMA4(wh11, hh);
                hh = hv[12]; FMA4(wh12, hh);
                hh = hv[13]; FMA4(wh13, hh);
                hh = hv[14]; FMA4(wh14, hh);
                hh = hv[15]; FMA4(wh15, hh);
                float4 xt = *(const float4*)&xbuf[cch & 1][s][0];       // broadcast
                FMA4(wx, xt);
                float acc = (a0 + a1) + (a2 + a3);
                float act = fmaf(sc_out, fast_rcp(1.0f + exp2f(sc_in2 * acc)), sc_off);
                float gi = __shfl(act, base,      64);
                float gf = __shfl(act, base + 16, 64);
                float gg = __shfl(act, base + 32, 64);
                float go = __shfl(act, base + 48, 64);
                c = fmaf(gf, c, gi * gg);
                float th = 1.0f - 2.0f * fast_rcp(exp2f(2.0f * L2E * c) + 1.0f);
                float h = go * th;
                if (lane < 16) h1buf[n & 1][j] = h;
            }
        } else {
            if (n >= 1) {
                float a0 = bias, a1 = 0.f, a2 = 0.f, a3 = 0.f;
                const float4* hv = (const float4*)h1buf[(n + 1) & 1] + (half << 3); // h1(n-1)
                float4 hh;
                hh = hv[0]; FMA4(wh0, hh);
                hh = hv[1]; FMA4(wh1, hh);
                hh = hv[2]; FMA4(wh2, hh);
                hh = hv[3]; FMA4(wh3, hh);
                hh = hv[4]; FMA4(wh4, hh);
                hh = hv[5]; FMA4(wh5, hh);
                hh = hv[6]; FMA4(wh6, hh);
                hh = hv[7]; FMA4(wh7, hh);
                const float4* h2v = (const float4*)h2buf[n & 1] + (half << 2);      // h2(n-2)
                hh = h2v[0]; FMA4(wh8,  hh);
                hh = h2v[1]; FMA4(wh9,  hh);
                hh = h2v[2]; FMA4(wh10, hh);
                hh = h2v[3]; FMA4(wh11, hh);
                float part = (a0 + a1) + (a2 + a3);
                float acc = part + __shfl_xor(part, 1, 64);   // combine lane pair
                float act = fmaf(sc_out, fast_rcp(1.0f + exp2f(sc_in2 * acc)), sc_off);
                float gi = __shfl(act, base,      64);
                float gf = __shfl(act, base + 16, 64);
                float gg = __shfl(act, base + 32, 64);
                float go = __shfl(act, base + 48, 64);
                c = fmaf(gf, c, gi * gg);
                float th = 1.0f - 2.0f * fast_rcp(exp2f(2.0f * L2E * c) + 1.0f);
                float h = go * th;
                if ((lane & 49) == 0) {            // type==0 && half==0
                    h2buf[(n + 1) & 1][j] = h;
                    outb[(size_t)(n - 1) * H2 + j] = h;
                }
            }
        }
        __syncthreads();
    }
#undef FMA4
}

extern "C" void kernel_launch(void* const* d_in, const int* in_sizes, int n_in,
                              void* d_out, int out_size, void* d_ws, size_t ws_size,
                              hipStream_t stream) {
    const float* x     = (const float*)d_in[0];
    const float* W_ih1 = (const float*)d_in[1];
    const float* W_hh1 = (const float*)d_in[2];
    const float* b_ih1 = (const float*)d_in[3];
    const float* b_hh1 = (const float*)d_in[4];
    const float* W_ih2 = (const float*)d_in[5];
    const float* W_hh2 = (const float*)d_in[6];
    const float* b_ih2 = (const float*)d_in[7];
    const float* b_hh2 = (const float*)d_in[8];
    float* out = (float*)d_out;

    lstm2_fused_v5<<<dim3(BATCH), dim3(NTHREADS), 0, stream>>>(
        x, W_ih1, W_hh1, b_ih1, b_hh1, W_ih2, W_hh2, b_ih2, b_hh2, out);
}